// Round 8
// baseline (1679.471 us; speedup 1.0000x reference)
//
#include <hip/hip_runtime.h>
#include <hip/hip_bf16.h>
#include <hip/hip_fp16.h>
#include <math.h>

#define DH 10      // hidden dim
#define DE 3       // edge attr dim
#define DIN 3      // input dim
#define REC 20     // fp32 D record: 20 floats = 80B
#define SHU 16     // fp16 S record stride in uints: 64B-ALIGNED (10 used) -> 1 line/record
#define NSL 7      // src slices: p = src>>15 (exact); valid for N <= 229376
#define ND 256     // dsts per gather block
#define NDSH 8
#define PSC 32     // scatter blocks: 4/XCD x 1.4MB tail-line set -> L2-resident
#define SCT 1024   // scatter block threads
#define GT 512     // gather block threads: 8 waves; 4 blk/CU (wave-limited) -> 782<=1024 co-resident, ~24 waves/CU
#define MAXC 5504  // static LDS cursor bound: NSL*ngb <= 5504 (N <= ~201k)
#define DREC_S 21  // padded LDS stride for D-recs  (gcd(21,32)=1)
#define ACC_S 11   // padded LDS stride for acc     (gcd(11,32)=1)
#define OVFCAP (1 << 20)   // overflow side-list capacity
#define PBIN 16    // graph bins per pooling block

typedef unsigned int u32;
typedef u32 u2v __attribute__((ext_vector_type(2)));   // nontemporal-load-compatible

__device__ __forceinline__ u32 pack_h2(float a, float b) {
    union { __half2 h; u32 u; } cv;
    cv.h = __floats2half2_rn(a, b);
    return cv.u;
}
__device__ __forceinline__ float2 unpack_h2(u32 u) {
    union { u32 u; __half2 h; } cv; cv.u = u;
    return __half22float2(cv.h);
}

// ---------------------------------------------------------------------------
// Per-node records. D (fp32, dst side, biases folded). S (fp16 packed).
// ---------------------------------------------------------------------------
__device__ __forceinline__ void compute_records_h(
    const float* __restrict__ hh,
    const float* __restrict__ fW, const float* __restrict__ fb,
    const float* __restrict__ sW, const float* __restrict__ sb,
    float* __restrict__ Dout, u32* __restrict__ Sout)
{
    float fsv[DH], ssv[DH];
#pragma unroll
    for (int j = 0; j < DH; ++j) {
        float fd = fb[j], sd = sb[j], fs = 0.f, ss = 0.f;
#pragma unroll
        for (int k = 0; k < DH; ++k) {
            fd += hh[k] * fW[j*23 + k];
            fs += hh[k] * fW[j*23 + 10 + k];
            sd += hh[k] * sW[j*23 + k];
            ss += hh[k] * sW[j*23 + 10 + k];
        }
        Dout[j]      = fd;
        Dout[DH + j] = sd;
        fsv[j] = fs;
        ssv[j] = ss;
    }
#pragma unroll
    for (int j = 0; j < 5; ++j) {
        Sout[j]     = pack_h2(fsv[2*j], fsv[2*j+1]);
        Sout[5 + j] = pack_h2(ssv[2*j], ssv[2*j+1]);
    }
}

// fp32 variant for the fallback path
__device__ __forceinline__ void compute_records(
    const float* __restrict__ hh,
    const float* __restrict__ fW, const float* __restrict__ fb,
    const float* __restrict__ sW, const float* __restrict__ sb,
    float* __restrict__ Dout, float* __restrict__ Sout)
{
#pragma unroll
    for (int j = 0; j < DH; ++j) {
        float fd = fb[j], sd = sb[j], fs = 0.f, ss = 0.f;
#pragma unroll
        for (int k = 0; k < DH; ++k) {
            fd += hh[k] * fW[j*23 + k];
            fs += hh[k] * fW[j*23 + 10 + k];
            sd += hh[k] * sW[j*23 + k];
            ss += hh[k] * sW[j*23 + 10 + k];
        }
        Dout[j]      = fd;
        Dout[DH + j] = sd;
        Sout[j]      = fs;
        Sout[DH + j] = ss;
    }
}

// ---------------------------------------------------------------------------
__global__ void zero_small(int* __restrict__ ovfh,
                           float* __restrict__ gsum, float* __restrict__ gcnt, int G)
{
    int i = blockIdx.x * blockDim.x + threadIdx.x;
    if (i == 0) *ovfh = 0;
    if (i < G * DH) gsum[i] = 0.f;
    if (i < G) gcnt[i] = 0.f;
}

// ---------------------------------------------------------------------------
// P0: h0 = relu(x@preW.T+preb); layer-1 records
// ---------------------------------------------------------------------------
__global__ void node_pre_h(const float* __restrict__ x,
                           const float* __restrict__ preW, const float* __restrict__ preb,
                           const float* __restrict__ fW, const float* __restrict__ fb,
                           const float* __restrict__ sW, const float* __restrict__ sb,
                           float* __restrict__ h, float* __restrict__ D, u32* __restrict__ Sh,
                           int N)
{
    __shared__ float lpW[30], lpb[10], lfW[230], lfb[10], lsW[230], lsb[10];
    for (int i = threadIdx.x; i < 30;  i += blockDim.x) lpW[i] = preW[i];
    for (int i = threadIdx.x; i < 10;  i += blockDim.x) { lpb[i] = preb[i]; lfb[i] = fb[i]; lsb[i] = sb[i]; }
    for (int i = threadIdx.x; i < 230; i += blockDim.x) { lfW[i] = fW[i]; lsW[i] = sW[i]; }
    __syncthreads();

    int n = blockIdx.x * blockDim.x + threadIdx.x;
    if (n >= N) return;

    float x0 = x[(size_t)n*3], x1 = x[(size_t)n*3+1], x2 = x[(size_t)n*3+2];
    float hh[DH];
#pragma unroll
    for (int j = 0; j < DH; ++j)
        hh[j] = fmaxf(lpb[j] + x0*lpW[j*3] + x1*lpW[j*3+1] + x2*lpW[j*3+2], 0.f);

    float* hp = h + (size_t)n * DH;
#pragma unroll
    for (int j = 0; j < DH; ++j) hp[j] = hh[j];

    compute_records_h(hh, lfW, lfb, lsW, lsb, D + (size_t)n*REC, Sh + (size_t)n*SHU);
}

// ---------------------------------------------------------------------------
// Block-private scatter. R6 diagnosis: old scatter sat at a per-transaction
// fabric wall (6.4M device-scope atomics + 6.4M partial-line stores; HPAD &
// XCD-key probes both null). Fix kills BOTH transaction classes:
//  - cursors live in LDS (zero per-edge global atomics);
//  - each block appends to PRIVATE sub-lists (b, slice, gblock); its active
//    tail-line set is C*64B = 350KB, 4 blocks/XCD -> 1.4MB, L2-resident, so
//    ~8 records coalesce per 64B writeback (NORMAL stores, not nt).
// Record 8B: w0 = srclow15 | dstlow8<<15 | a2q9<<23 ; w1 = h2(a0,a1).
// ---------------------------------------------------------------------------
__global__ __launch_bounds__(SCT, 1) void scatter_local(
    const int* __restrict__ ei, const float* __restrict__ attr,
    int* __restrict__ cnt2, uint2* __restrict__ lists,
    uint4* __restrict__ ovf, int* __restrict__ ovfh,
    int E, int ngb, int C, int cap, int EB)
{
    __shared__ int lcnt[MAXC];
    for (int i = threadIdx.x; i < C; i += SCT) lcnt[i] = 0;
    __syncthreads();

    int b = blockIdx.x;
    int start = b * EB;
    int end = start + EB; if (end > E) end = E;

    for (int e = start + threadIdx.x; e < end; e += SCT) {
        int src = __builtin_nontemporal_load(ei + e);
        int dst = __builtin_nontemporal_load(ei + (size_t)E + e);
        float a0 = __builtin_nontemporal_load(attr + (size_t)e * DE);
        float a1 = __builtin_nontemporal_load(attr + (size_t)e * DE + 1);
        float a2 = __builtin_nontemporal_load(attr + (size_t)e * DE + 2);

        int p   = src >> 15;
        int gb  = dst >> NDSH;
        int bin = p * ngb + gb;
        float a2c = fminf(fmaxf(a2, 0.f), 1.0f);
        u32 a2q = (u32)(a2c * 511.0f + 0.5f);
        u32 w0 = (u32)(src & 0x7FFF) | ((u32)(dst & (ND-1)) << 15) | (a2q << 23);
        u32 w1 = pack_h2(a0, a1);

        int pos = atomicAdd(&lcnt[bin], 1);            // LDS atomic only
        if (pos < cap) {
            lists[((size_t)b * C + bin) * cap + pos] = make_uint2(w0, w1);
        } else {
            int op = atomicAdd(ovfh, 1);               // rare (cap is +4.5 sigma)
            u32 a2q14 = (u32)(a2c * 16383.0f + 0.5f);
            if (op < OVFCAP) ovf[op] = make_uint4((u32)dst, (u32)src | (a2q14 << 18), w1, 0u);
        }
    }
    __syncthreads();

    // dense dump of this block's counts (bin-major: gather reads PSC
    // consecutive ints per (slice, gblock))
    for (int i = threadIdx.x; i < C; i += SCT) {
        int c = lcnt[i]; if (c > cap) c = cap;
        cnt2[(size_t)i * PSC + b] = c;
    }
}

// ---------------------------------------------------------------------------
// Gather: one block per 256-dst gatherblock, 512 threads (8 waves), 32KB LDS.
// Geometry chosen against the R3/R4/R5 evidence: wave-limit gives 4 blk/CU
// -> capacity 1024 >= 782 blocks = CO-RESIDENT single generation (R3/R5
// failure excluded) at ~24 waves/CU (R4's 3-waves/SIMD starvation excluded;
// R0's proven gather ran 255us at 20 waves/CU). Per slice: 16-lane group g
// owns scatter-block g's sub-list (~36.5 recs -> 2.3/lane). Per-dst
// segmentation via LDS float atomics (padded strides, ~conflict-free).
// ---------------------------------------------------------------------------
__global__ __launch_bounds__(GT, 8) void gather_blocks(
    const int* __restrict__ cnt2, const uint2* __restrict__ lists, int cap,
    const float* __restrict__ D, const u32* __restrict__ ShU,
    const float* __restrict__ Wf, const float* __restrict__ Ws,
    float* __restrict__ accg, int N, int ngb)
{
    __shared__ float s_drec[ND * DREC_S];   // 21.0 KB
    __shared__ float s_acc [ND * ACC_S];    // 11.0 KB  (32 KB total)

    int gb   = blockIdx.x;
    int base = gb << NDSH;
    if (base >= N) return;
    int cn = N - base; if (cn > ND) cn = ND;
    int C = NSL * ngb;
    const u2v* listsv = (const u2v*)lists;

    for (int i = threadIdx.x; i < cn * REC; i += GT) {
        int nl = i / REC, j = i - nl * REC;
        s_drec[nl * DREC_S + j] = __builtin_nontemporal_load(D + (size_t)base * REC + i);
    }
    for (int i = threadIdx.x; i < cn * ACC_S; i += GT) s_acc[i] = 0.f;

    float wf[30], wsr[30];   // wave-uniform -> SGPRs
#pragma unroll
    for (int i = 0; i < 30; ++i) {
        int j = i / 3, t = i % 3;
        wf[i]  = Wf[j*23 + 20 + t];
        wsr[i] = Ws[j*23 + 20 + t];
    }
    __syncthreads();

    int g   = threadIdx.x >> 4;        // scatter-block index [0,32)
    int sub = threadIdx.x & 15;

    for (int p = 0; p < NSL; ++p) {
        int bin = p * ngb + gb;
        int cc = cnt2[(size_t)bin * PSC + g]; if (cc > cap) cc = cap;
        size_t rb = ((size_t)g * C + bin) * (size_t)cap;
        int pb = p << 15;

        for (int q = sub; q < cc; q += 16) {
            u2v r = __builtin_nontemporal_load(listsv + rb + q);

            int   srclow = (int)(r.x & 0x7FFFu);
            int   dl     = (int)((r.x >> 15) & (u32)(ND-1));
            float a2     = (float)(r.x >> 23) * (1.0f / 511.0f);
            float2 a01   = unpack_h2(r.y);
            float a0 = a01.x, a1 = a01.y;
            int   src    = pb + srclow;

            const uint4* sp = (const uint4*)(ShU + (size_t)src * SHU);
            uint4 A = sp[0];
            uint4 B = sp[1];
            uint2 Cw = *(const uint2*)(sp + 2);
            u32 u[10] = {A.x, A.y, A.z, A.w, B.x, B.y, B.z, B.w, Cw.x, Cw.y};

            const float* dr = s_drec + dl * DREC_S;
            float*       ac = s_acc  + dl * ACC_S;
#pragma unroll
            for (int j = 0; j < 5; ++j) {
                float2 f1 = unpack_h2(u[j]);       // fs[2j], fs[2j+1]
                float2 f2 = unpack_h2(u[5 + j]);   // ss[2j], ss[2j+1]
                {
                    const int jj = 2*j;
                    float pf = dr[jj]      + f1.x + a0*wf[jj*3]  + a1*wf[jj*3+1]  + a2*wf[jj*3+2];
                    float ps = dr[DH + jj] + f2.x + a0*wsr[jj*3] + a1*wsr[jj*3+1] + a2*wsr[jj*3+2];
                    float sg  = __builtin_amdgcn_rcpf(1.0f + __expf(-pf));
                    float sp2 = fmaxf(ps, 0.f) + __logf(1.0f + __expf(-fabsf(ps)));
                    atomicAdd(ac + jj, sg * sp2);
                }
                {
                    const int jj = 2*j + 1;
                    float pf = dr[jj]      + f1.y + a0*wf[jj*3]  + a1*wf[jj*3+1]  + a2*wf[jj*3+2];
                    float ps = dr[DH + jj] + f2.y + a0*wsr[jj*3] + a1*wsr[jj*3+1] + a2*wsr[jj*3+2];
                    float sg  = __builtin_amdgcn_rcpf(1.0f + __expf(-pf));
                    float sp2 = fmaxf(ps, 0.f) + __logf(1.0f + __expf(-fabsf(ps)));
                    atomicAdd(ac + jj, sg * sp2);
                }
            }
        }
        __syncthreads();   // slice lockstep; also fences acc before store
    }

    for (int i = threadIdx.x; i < cn * DH; i += GT) {
        int nl = i / DH, j = i - nl * DH;
        accg[(size_t)base * DH + i] = s_acc[nl * ACC_S + j];
    }
}

// ---------------------------------------------------------------------------
// Overflow pass: tiny (~1e2-1e3 edges), global atomics. (OLD record format.)
// ---------------------------------------------------------------------------
__global__ void ovf_pass(const uint4* __restrict__ ovf, const int* __restrict__ ovfh,
                         const float* __restrict__ D, const u32* __restrict__ ShU,
                         const float* __restrict__ Wf, const float* __restrict__ Ws,
                         float* __restrict__ accg)
{
    __shared__ float wf[30], wsr[30];
    if (threadIdx.x < 30) {
        int j = threadIdx.x / 3, t = threadIdx.x % 3;
        wf[threadIdx.x]  = Wf[j*23 + 20 + t];
        wsr[threadIdx.x] = Ws[j*23 + 20 + t];
    }
    __syncthreads();

    int oc = *ovfh; if (oc > OVFCAP) oc = OVFCAP;
    for (int i = blockIdx.x * blockDim.x + threadIdx.x; i < oc;
         i += gridDim.x * blockDim.x) {
        uint4 e = ovf[i];
        int dst = (int)e.x;
        u32 w0 = e.y;
        int src = (int)(w0 & 0x3FFFFu);
        float a2 = (float)(w0 >> 18) * (1.0f / 16383.0f);
        float2 a01 = unpack_h2(e.z);
        float a0 = a01.x, a1 = a01.y;

        float dr[REC];
        const float4* dp = (const float4*)(D + (size_t)dst * REC);
#pragma unroll
        for (int k = 0; k < 5; ++k) ((float4*)dr)[k] = dp[k];

        const uint4* sp = (const uint4*)(ShU + (size_t)src * SHU);
        uint4 A = sp[0];
        uint4 B = sp[1];
        uint2 C = *(const uint2*)(sp + 2);
        u32 u[10] = {A.x, A.y, A.z, A.w, B.x, B.y, B.z, B.w, C.x, C.y};
        float s[20];
#pragma unroll
        for (int k = 0; k < 10; ++k) {
            float2 f = unpack_h2(u[k]);
            s[2*k] = f.x; s[2*k+1] = f.y;
        }
        float* ap = accg + (size_t)dst * DH;
#pragma unroll
        for (int j = 0; j < DH; ++j) {
            float pf = dr[j]      + s[j]      + a0*wf[j*3]  + a1*wf[j*3+1]  + a2*wf[j*3+2];
            float ps = dr[DH + j] + s[DH + j] + a0*wsr[j*3] + a1*wsr[j*3+1] + a2*wsr[j*3+2];
            float sg  = __builtin_amdgcn_rcpf(1.0f + __expf(-pf));
            float sp2 = fmaxf(ps, 0.f) + __logf(1.0f + __expf(-fabsf(ps)));
            atomicAdd(ap + j, sg * sp2);
        }
    }
}

// ---------------------------------------------------------------------------
// Layer-1 epilogue: h = relu(h + acc); records for layer 2
// ---------------------------------------------------------------------------
__global__ void node_mid_h(float* __restrict__ h, const float* __restrict__ acc,
                           const float* __restrict__ fW, const float* __restrict__ fb,
                           const float* __restrict__ sW, const float* __restrict__ sb,
                           float* __restrict__ D, u32* __restrict__ Sh, int N)
{
    __shared__ float lfW[230], lfb[10], lsW[230], lsb[10];
    for (int i = threadIdx.x; i < 230; i += blockDim.x) { lfW[i] = fW[i]; lsW[i] = sW[i]; }
    for (int i = threadIdx.x; i < 10;  i += blockDim.x) { lfb[i] = fb[i]; lsb[i] = sb[i]; }
    __syncthreads();
    int n = blockIdx.x * blockDim.x + threadIdx.x;
    if (n >= N) return;
    float* hp = h + (size_t)n * DH;
    const float* ap = acc + (size_t)n * DH;
    float hh[DH];
#pragma unroll
    for (int j = 0; j < DH; ++j) {
        hh[j] = fmaxf(hp[j] + ap[j], 0.f);
        hp[j] = hh[j];
    }
    compute_records_h(hh, lfW, lfb, lsW, lsb, D + (size_t)n*REC, Sh + (size_t)n*SHU);
}

// ---------------------------------------------------------------------------
// Layer-2 epilogue + pooling: segmented block-local reduction (batch sorted).
// ---------------------------------------------------------------------------
__global__ void node_pool(const float* __restrict__ h, const float* __restrict__ acc,
                          const int* __restrict__ batch,
                          float* __restrict__ gsum, float* __restrict__ gcnt, int N)
{
    __shared__ float lg[PBIN * DH];
    __shared__ float lc[PBIN];

    int base = blockIdx.x * blockDim.x;
    int n = base + threadIdx.x;

    for (int i = threadIdx.x; i < PBIN * DH; i += blockDim.x) lg[i] = 0.f;
    if (threadIdx.x < PBIN) lc[threadIdx.x] = 0.f;
    __syncthreads();

    int b0 = batch[base];   // uniform across block (sorted)

    if (n < N) {
        int b = batch[n];
        int off = b - b0;
        const float* hp = h + (size_t)n * DH;
        const float* ap = acc + (size_t)n * DH;
        float v[DH];
#pragma unroll
        for (int j = 0; j < DH; ++j) v[j] = fmaxf(hp[j] + ap[j], 0.f);

        if (off < PBIN) {
#pragma unroll
            for (int j = 0; j < DH; ++j) atomicAdd(&lg[off * DH + j], v[j]);
            atomicAdd(&lc[off], 1.f);
        } else {   // statistically impossible (256 sorted nodes span ~4 graphs)
            float* gp = gsum + (size_t)b * DH;
#pragma unroll
            for (int j = 0; j < DH; ++j) atomicAdd(gp + j, v[j]);
            atomicAdd(gcnt + b, 1.f);
        }
    }
    __syncthreads();

    for (int i = threadIdx.x; i < PBIN * DH; i += blockDim.x) {
        int g = i / DH;
        if (lc[g] > 0.f)
            atomicAdd(&gsum[(size_t)(b0 + g) * DH + (i - g * DH)], lg[i]);
    }
    if (threadIdx.x < PBIN && lc[threadIdx.x] > 0.f)
        atomicAdd(&gcnt[b0 + threadIdx.x], lc[threadIdx.x]);
}

// ---------------------------------------------------------------------------
// Fallback path kernels (fp32 atomic path; used only if ws too small / N too big)
// ---------------------------------------------------------------------------
__global__ void node_pre_f32(const float* __restrict__ x,
                             const float* __restrict__ preW, const float* __restrict__ preb,
                             const float* __restrict__ fW, const float* __restrict__ fb,
                             const float* __restrict__ sW, const float* __restrict__ sb,
                             float* __restrict__ h, float* __restrict__ D, float* __restrict__ S,
                             float* __restrict__ agg,
                             float* __restrict__ gsum, float* __restrict__ gcnt, int N, int G)
{
    __shared__ float lpW[30], lpb[10], lfW[230], lfb[10], lsW[230], lsb[10];
    for (int i = threadIdx.x; i < 30;  i += blockDim.x) lpW[i] = preW[i];
    for (int i = threadIdx.x; i < 10;  i += blockDim.x) { lpb[i] = preb[i]; lfb[i] = fb[i]; lsb[i] = sb[i]; }
    for (int i = threadIdx.x; i < 230; i += blockDim.x) { lfW[i] = fW[i]; lsW[i] = sW[i]; }
    __syncthreads();
    int n = blockIdx.x * blockDim.x + threadIdx.x;
    if (n < G * DH) gsum[n] = 0.f;
    if (n < G)      gcnt[n] = 0.f;
    if (n >= N) return;
    float x0 = x[(size_t)n*3], x1 = x[(size_t)n*3+1], x2 = x[(size_t)n*3+2];
    float hh[DH];
#pragma unroll
    for (int j = 0; j < DH; ++j)
        hh[j] = fmaxf(lpb[j] + x0*lpW[j*3] + x1*lpW[j*3+1] + x2*lpW[j*3+2], 0.f);
    float* hp = h + (size_t)n * DH;
    float* ap = agg + (size_t)n * DH;
#pragma unroll
    for (int j = 0; j < DH; ++j) { hp[j] = hh[j]; ap[j] = 0.f; }
    compute_records(hh, lfW, lfb, lsW, lsb, D + (size_t)n*REC, S + (size_t)n*REC);
}

__global__ void edge_pass(const int* __restrict__ ei, const float* __restrict__ attr,
                          const float* __restrict__ D, const float* __restrict__ S,
                          const float* __restrict__ Wf, const float* __restrict__ Ws,
                          float* __restrict__ agg, int E)
{
    __shared__ float wfe[30], wse[30];
    if (threadIdx.x < 30) {
        int j = threadIdx.x / 3, t = threadIdx.x % 3;
        wfe[threadIdx.x] = Wf[j*23 + 20 + t];
        wse[threadIdx.x] = Ws[j*23 + 20 + t];
    }
    __syncthreads();
    int e = blockIdx.x * blockDim.x + threadIdx.x;
    if (e >= E) return;
    int src = ei[e];
    int dst = ei[(size_t)E + e];
    const float* eap = attr + (size_t)e * DE;
    float ea0 = eap[0], ea1 = eap[1], ea2 = eap[2];
    float drec[REC], srec[REC];
    const float4* Dp = (const float4*)(D + (size_t)dst * REC);
    const float4* Sp = (const float4*)(S + (size_t)src * REC);
#pragma unroll
    for (int i = 0; i < 5; ++i) { ((float4*)drec)[i] = Dp[i]; ((float4*)srec)[i] = Sp[i]; }
    float* ap = agg + (size_t)dst * DH;
#pragma unroll
    for (int j = 0; j < DH; ++j) {
        float pf = drec[j]      + srec[j]      + ea0*wfe[j*3] + ea1*wfe[j*3+1] + ea2*wfe[j*3+2];
        float ps = drec[DH + j] + srec[DH + j] + ea0*wse[j*3] + ea1*wse[j*3+1] + ea2*wse[j*3+2];
        float sg = 1.0f / (1.0f + __expf(-pf));
        float sp = fmaxf(ps, 0.f) + log1pf(__expf(-fabsf(ps)));
        atomicAdd(ap + j, sg * sp);
    }
}

__global__ void node_mid(float* __restrict__ h, float* __restrict__ agg,
                         const float* __restrict__ fW, const float* __restrict__ fb,
                         const float* __restrict__ sW, const float* __restrict__ sb,
                         float* __restrict__ D, float* __restrict__ S, int N)
{
    __shared__ float lfW[230], lfb[10], lsW[230], lsb[10];
    for (int i = threadIdx.x; i < 230; i += blockDim.x) { lfW[i] = fW[i]; lsW[i] = sW[i]; }
    for (int i = threadIdx.x; i < 10;  i += blockDim.x) { lfb[i] = fb[i]; lsb[i] = sb[i]; }
    __syncthreads();
    int n = blockIdx.x * blockDim.x + threadIdx.x;
    if (n >= N) return;
    float* hp = h + (size_t)n * DH;
    float* ap = agg + (size_t)n * DH;
    float hh[DH];
#pragma unroll
    for (int j = 0; j < DH; ++j) {
        hh[j] = fmaxf(hp[j] + ap[j], 0.f);
        hp[j] = hh[j];
        ap[j] = 0.f;
    }
    compute_records(hh, lfW, lfb, lsW, lsb, D + (size_t)n*REC, S + (size_t)n*REC);
}

__global__ void node_post(const float* __restrict__ h, const float* __restrict__ agg,
                          const int* __restrict__ batch,
                          float* __restrict__ gsum, float* __restrict__ gcnt, int N)
{
    int n = blockIdx.x * blockDim.x + threadIdx.x;
    if (n >= N) return;
    int b = batch[n];
    const float* hp = h + (size_t)n * DH;
    const float* ap = agg + (size_t)n * DH;
    float* gp = gsum + (size_t)b * DH;
#pragma unroll
    for (int j = 0; j < DH; ++j)
        atomicAdd(gp + j, fmaxf(hp[j] + ap[j], 0.f));
    atomicAdd(gcnt + b, 1.f);
}

// ---------------------------------------------------------------------------
// MLP head: one block (128 threads) per graph.
// ---------------------------------------------------------------------------
__global__ void mlp_head(const float* __restrict__ gsum, const float* __restrict__ gcnt,
                         const float* __restrict__ fc1W, const float* __restrict__ fc1b,
                         const float* __restrict__ fc2W, const float* __restrict__ fc2b,
                         const float* __restrict__ outW, const float* __restrict__ outb,
                         float* __restrict__ out, int G)
{
    __shared__ float g[DH], a1[128], a2[128];
    int gid = blockIdx.x;
    int t = threadIdx.x;
    if (t < DH) {
        float c = fmaxf(gcnt[gid], 1.0f);
        g[t] = gsum[(size_t)gid*DH + t] / c;
    }
    __syncthreads();
    {
        float acc = fc1b[t];
        const float* w = fc1W + (size_t)t * DH;
#pragma unroll
        for (int k = 0; k < DH; ++k) acc += w[k] * g[k];
        a1[t] = fmaxf(acc, 0.f);
    }
    __syncthreads();
    {
        float acc = fc2b[t];
        const float* w = fc2W + (size_t)t * 128;
#pragma unroll 8
        for (int k = 0; k < 128; ++k) acc += w[k] * a1[k];
        a2[t] = fmaxf(acc, 0.f);
    }
    __syncthreads();
    if (t < 3) {
        float acc = outb[t];
        const float* w = outW + (size_t)t * 128;
#pragma unroll 8
        for (int k = 0; k < 128; ++k) acc += w[k] * a2[k];
        out[(size_t)gid*3 + t] = acc;
    }
}

// ---------------------------------------------------------------------------
extern "C" void kernel_launch(void* const* d_in, const int* in_sizes, int n_in,
                              void* d_out, int out_size, void* d_ws, size_t ws_size,
                              hipStream_t stream)
{
    const float* x     = (const float*)d_in[0];
    const int*   ei    = (const int*)  d_in[1];
    const float* attr  = (const float*)d_in[2];
    const int*   batch = (const int*)  d_in[3];
    const float* preW  = (const float*)d_in[4];
    const float* preb  = (const float*)d_in[5];
    const float* f1W   = (const float*)d_in[6];
    const float* f1b   = (const float*)d_in[7];
    const float* s1W   = (const float*)d_in[8];
    const float* s1b   = (const float*)d_in[9];
    const float* f2W   = (const float*)d_in[10];
    const float* f2b   = (const float*)d_in[11];
    const float* s2W   = (const float*)d_in[12];
    const float* s2b   = (const float*)d_in[13];
    const float* fc1W  = (const float*)d_in[14];
    const float* fc1b  = (const float*)d_in[15];
    const float* fc2W  = (const float*)d_in[16];
    const float* fc2b  = (const float*)d_in[17];
    const float* outW  = (const float*)d_in[18];
    const float* outb  = (const float*)d_in[19];

    const int N = in_sizes[0] / DIN;          // 200000
    const int E = in_sizes[1] / 2;            // 6400000
    const int G = out_size / 3;               // 1024
    const int ngb = (N + ND - 1) >> NDSH;     // 782 gather blocks
    const int C = NSL * ngb;                  // 5474 bins per scatter block
    const int EB = (E + PSC - 1) / PSC;       // 200000 edges per scatter block

    const int TB = 256;
    const int nb = (N + TB - 1) / TB;
    const int zb = (G * DH + TB - 1) / TB;

    // ---- workspace layout ----
    size_t f_off = 0;
    float* ws = (float*)d_ws;
    float* h    = ws + f_off; f_off += (size_t)N * DH;
    float* D    = ws + f_off; f_off += (size_t)N * REC;
    f_off = (f_off + 15) & ~(size_t)15;                        // 64B-align Sh
    u32*   Sh   = (u32*)(ws + f_off); f_off += (size_t)N * SHU;
    float* acc  = ws + f_off; f_off += (size_t)N * DH;
    float* gsum = ws + f_off; f_off += (size_t)G * DH;
    float* gcnt = ws + f_off; f_off += G;
    f_off = (f_off + 15) & ~(size_t)15;
    int* cnt2   = (int*)(ws + f_off); f_off += (size_t)C * PSC;
    int* ovfh   = (int*)(ws + f_off); f_off += 1;
    f_off = (f_off + 15) & ~(size_t)15;
    uint4* ovf  = (uint4*)(ws + f_off); f_off += (size_t)OVFCAP * 4;
    f_off = (f_off + 15) & ~(size_t)15;
    uint2* lists = (uint2*)(ws + f_off);

    size_t core_bytes = f_off * sizeof(float);
    long long budget = (long long)ws_size - (long long)core_bytes;
    int cap = 0;
    if (budget > 0) cap = (int)(budget / ((long long)PSC * C * 8));
    if (cap > 64) cap = 64;
    // records/cell ~ Poisson(36.5): cap=64 is +4.5 sigma -> ovf ~ O(10)

    if (cap >= 56 && N <= NSL * 32768 && C <= MAXC && ngb <= 1024) {
        // ===== block-private sub-lists + co-resident 8-wave gather path =====
        zero_small<<<zb, TB, 0, stream>>>(ovfh, gsum, gcnt, G);
        node_pre_h<<<nb, TB, 0, stream>>>(x, preW, preb, f1W, f1b, s1W, s1b,
                                          h, D, Sh, N);
        scatter_local<<<PSC, SCT, 0, stream>>>(ei, attr, cnt2, lists, ovf, ovfh,
                                               E, ngb, C, cap, EB);

        gather_blocks<<<ngb, GT, 0, stream>>>(cnt2, lists, cap, D, Sh,
                                              f1W, s1W, acc, N, ngb);
        ovf_pass<<<256, 256, 0, stream>>>(ovf, ovfh, D, Sh, f1W, s1W, acc);
        node_mid_h<<<nb, TB, 0, stream>>>(h, acc, f2W, f2b, s2W, s2b, D, Sh, N);

        gather_blocks<<<ngb, GT, 0, stream>>>(cnt2, lists, cap, D, Sh,
                                              f2W, s2W, acc, N, ngb);
        ovf_pass<<<256, 256, 0, stream>>>(ovf, ovfh, D, Sh, f2W, s2W, acc);
        node_pool<<<nb, TB, 0, stream>>>(h, acc, batch, gsum, gcnt, N);
        mlp_head<<<G, 128, 0, stream>>>(gsum, gcnt, fc1W, fc1b, fc2W, fc2b,
                                        outW, outb, (float*)d_out, G);
    } else {
        // ===== fallback: fp32 atomic path =====
        size_t o = 0;
        float* fh    = ws + o; o += (size_t)N * DH;
        float* agg   = ws + o; o += (size_t)N * DH;
        float* fD    = ws + o; o += (size_t)N * REC;
        float* fS    = ws + o; o += (size_t)N * REC;
        float* fgsum = ws + o; o += (size_t)G * DH;
        float* fgcnt = ws + o; o += G;

        const int eb = (E + TB - 1) / TB;
        node_pre_f32<<<nb, TB, 0, stream>>>(x, preW, preb, f1W, f1b, s1W, s1b,
                                            fh, fD, fS, agg, fgsum, fgcnt, N, G);
        edge_pass<<<eb, TB, 0, stream>>>(ei, attr, fD, fS, f1W, s1W, agg, E);
        node_mid<<<nb, TB, 0, stream>>>(fh, agg, f2W, f2b, s2W, s2b, fD, fS, N);
        edge_pass<<<eb, TB, 0, stream>>>(ei, attr, fD, fS, f2W, s2W, agg, E);
        node_post<<<nb, TB, 0, stream>>>(fh, agg, batch, fgsum, fgcnt, N);
        mlp_head<<<G, 128, 0, stream>>>(fgsum, fgcnt, fc1W, fc1b, fc2W, fc2b,
                                        outW, outb, (float*)d_out, G);
    }
}

// Round 9
// 931.700 us; speedup vs baseline: 1.8026x; 1.8026x over previous
//
#include <hip/hip_runtime.h>
#include <hip/hip_bf16.h>
#include <hip/hip_fp16.h>
#include <math.h>

#define DH 10      // hidden dim
#define DE 3       // edge attr dim
#define DIN 3      // input dim
#define REC 20     // fp32 D record: 20 floats = 80B
#define SHU 16     // fp16 S record stride in uints: 64B-ALIGNED (10 used) -> 1 line/record
#define VEC 4      // lanes cooperating per node in gather
#define SSH 15     // slice shift
#define NS 6       // slices 0..5 (slice 5 merged tail); slice = 32768*64B = 2MB (L2-resident)
#define WGN 1536   // persistent workgroups: 6/CU x 256 CUs EXACTLY (co-resident by construction)
#define MAXNPW 131 // max dst nodes per workgroup -> LDS 15.7KB, 6 blocks/CU = 94KB/CU
#define OVFCAP (1 << 20)   // overflow side-list capacity (1M recs, 16MB)
#define PBIN 16    // graph bins per pooling block (256 sorted nodes span <= ~4)

typedef unsigned int u32;
typedef u32 u2v __attribute__((ext_vector_type(2)));

__device__ __forceinline__ u32 pack_h2(float a, float b) {
    union { __half2 h; u32 u; } cv;
    cv.h = __floats2half2_rn(a, b);
    return cv.u;
}
__device__ __forceinline__ float2 unpack_h2(u32 u) {
    union { u32 u; __half2 h; } cv; cv.u = u;
    return __half22float2(cv.h);
}

// ---------------------------------------------------------------------------
// Per-node records. D (fp32, dst side, biases folded). S (fp16 packed).
// ---------------------------------------------------------------------------
__device__ __forceinline__ void compute_records_h(
    const float* __restrict__ hh,
    const float* __restrict__ fW, const float* __restrict__ fb,
    const float* __restrict__ sW, const float* __restrict__ sb,
    float* __restrict__ Dout, u32* __restrict__ Sout)
{
    float fsv[DH], ssv[DH];
#pragma unroll
    for (int j = 0; j < DH; ++j) {
        float fd = fb[j], sd = sb[j], fs = 0.f, ss = 0.f;
#pragma unroll
        for (int k = 0; k < DH; ++k) {
            fd += hh[k] * fW[j*23 + k];
            fs += hh[k] * fW[j*23 + 10 + k];
            sd += hh[k] * sW[j*23 + k];
            ss += hh[k] * sW[j*23 + 10 + k];
        }
        Dout[j]      = fd;
        Dout[DH + j] = sd;
        fsv[j] = fs;
        ssv[j] = ss;
    }
#pragma unroll
    for (int j = 0; j < 5; ++j) {
        Sout[j]     = pack_h2(fsv[2*j], fsv[2*j+1]);
        Sout[5 + j] = pack_h2(ssv[2*j], ssv[2*j+1]);
    }
}

// fp32 variant for the fallback path
__device__ __forceinline__ void compute_records(
    const float* __restrict__ hh,
    const float* __restrict__ fW, const float* __restrict__ fb,
    const float* __restrict__ sW, const float* __restrict__ sb,
    float* __restrict__ Dout, float* __restrict__ Sout)
{
#pragma unroll
    for (int j = 0; j < DH; ++j) {
        float fd = fb[j], sd = sb[j], fs = 0.f, ss = 0.f;
#pragma unroll
        for (int k = 0; k < DH; ++k) {
            fd += hh[k] * fW[j*23 + k];
            fs += hh[k] * fW[j*23 + 10 + k];
            sd += hh[k] * sW[j*23 + k];
            ss += hh[k] * sW[j*23 + 10 + k];
        }
        Dout[j]      = fd;
        Dout[DH + j] = sd;
        Sout[j]      = fs;
        Sout[DH + j] = ss;
    }
}

// ---------------------------------------------------------------------------
__global__ void zero_small(int* __restrict__ heads, int M, int* __restrict__ ovfh,
                           float* __restrict__ gsum, float* __restrict__ gcnt, int G)
{
    int i = blockIdx.x * blockDim.x + threadIdx.x;
    if (i < M) heads[i] = 0;
    if (i == 0) *ovfh = 0;
    if (i < G * DH) gsum[i] = 0.f;
    if (i < G) gcnt[i] = 0.f;
}

// ---------------------------------------------------------------------------
// P0: h0 = relu(x@preW.T+preb); layer-1 records
// ---------------------------------------------------------------------------
__global__ void node_pre_h(const float* __restrict__ x,
                           const float* __restrict__ preW, const float* __restrict__ preb,
                           const float* __restrict__ fW, const float* __restrict__ fb,
                           const float* __restrict__ sW, const float* __restrict__ sb,
                           float* __restrict__ h, float* __restrict__ D, u32* __restrict__ Sh,
                           int N)
{
    __shared__ float lpW[30], lpb[10], lfW[230], lfb[10], lsW[230], lsb[10];
    for (int i = threadIdx.x; i < 30;  i += blockDim.x) lpW[i] = preW[i];
    for (int i = threadIdx.x; i < 10;  i += blockDim.x) { lpb[i] = preb[i]; lfb[i] = fb[i]; lsb[i] = sb[i]; }
    for (int i = threadIdx.x; i < 230; i += blockDim.x) { lfW[i] = fW[i]; lsW[i] = sW[i]; }
    __syncthreads();

    int n = blockIdx.x * blockDim.x + threadIdx.x;
    if (n >= N) return;

    float x0 = x[(size_t)n*3], x1 = x[(size_t)n*3+1], x2 = x[(size_t)n*3+2];
    float hh[DH];
#pragma unroll
    for (int j = 0; j < DH; ++j)
        hh[j] = fmaxf(lpb[j] + x0*lpW[j*3] + x1*lpW[j*3+1] + x2*lpW[j*3+2], 0.f);

    float* hp = h + (size_t)n * DH;
#pragma unroll
    for (int j = 0; j < DH; ++j) hp[j] = hh[j];

    compute_records_h(hh, lfW, lfb, lsW, lsb, D + (size_t)n*REC, Sh + (size_t)n*SHU);
}

// ---------------------------------------------------------------------------
// One-pass scatter into capacity buckets keyed (slice, node). R0-proven form,
// byte-identical (R6 HPAD probe was null -> reverted to stride-1 cursors).
// Measured wall: ~8.6 fabric transactions/cycle (6.4M atomics + 6.4M partial-
// line stores); probes HPAD/XCD-key/ILP/private-lists all null or worse.
// Edge rec 8B: w0 = src(18) | a2q(14)<<18 ; w1 = h2(a0,a1).
// ---------------------------------------------------------------------------
__global__ void scatter_cap(const int* __restrict__ ei, const float* __restrict__ attr,
                            int* __restrict__ heads, uint2* __restrict__ csr,
                            uint4* __restrict__ ovf, int* __restrict__ ovfh,
                            int E, int N, int cap)
{
    int e = blockIdx.x * blockDim.x + threadIdx.x;
    if (e >= E) return;
    int src = __builtin_nontemporal_load(ei + e);
    int dst = __builtin_nontemporal_load(ei + (size_t)E + e);
    float a0 = __builtin_nontemporal_load(attr + (size_t)e * DE);
    float a1 = __builtin_nontemporal_load(attr + (size_t)e * DE + 1);
    float a2 = __builtin_nontemporal_load(attr + (size_t)e * DE + 2);
    int p = src >> SSH; if (p > NS - 1) p = NS - 1;
    u32 a2q = (u32)(fminf(fmaxf(a2, 0.f), 1.0f) * 16383.0f + 0.5f);
    u32 w0 = (u32)src | (a2q << 18);
    u32 w1 = pack_h2(a0, a1);

    size_t idx = (size_t)p * N + dst;
    int pos = atomicAdd(&heads[idx], 1);
    if (pos < cap) {
        csr[idx * cap + pos] = make_uint2(w0, w1);
    } else {
        int op = atomicAdd(ovfh, 1);
        if (op < OVFCAP) ovf[op] = make_uint4((u32)dst, w0, w1, 0u);
    }
}

// ---------------------------------------------------------------------------
// Persistent gather: R0-proven inner loop, occupancy raised 5->6 blocks/CU.
// Evidence: latency-bound in waves/CU (R4: 8w->470us, R0: 20w->255us; R8:
// geometry change regressed). Lever: npw 157->131 shrinks LDS 30->15.7KB ->
// launch_bounds(256,6); WGN=1536=6x256 exactly -> co-resident by construction
// (single generation, slice-lockstep, S-slice L2-resident), 24 waves/CU.
// VGPR budget 85 at 6 waves/EU; prior variants measured 24-44 -> no spill.
// ---------------------------------------------------------------------------
__global__ __launch_bounds__(256, 6) void gather_persist(
    const int* __restrict__ heads, const uint2* __restrict__ csr, int cap,
    const float* __restrict__ D, const u32* __restrict__ ShU,
    const float* __restrict__ Wf, const float* __restrict__ Ws,
    float* __restrict__ accg, int N, int npw)
{
    __shared__ float s_drec[MAXNPW * REC];   // 10.5 KB
    __shared__ float s_acc[MAXNPW * DH];     //  5.2 KB  (15.7 KB -> 6 blocks/CU)

    int base = blockIdx.x * npw;
    if (base >= N) return;
    int cn = N - base; if (cn > npw) cn = npw;

    for (int i = threadIdx.x; i < cn * REC; i += 256)
        s_drec[i] = __builtin_nontemporal_load(D + (size_t)base * REC + i);
    for (int i = threadIdx.x; i < cn * DH; i += 256)
        s_acc[i] = 0.f;

    float wf[30], wsr[30];   // wave-uniform -> SGPRs
#pragma unroll
    for (int i = 0; i < 30; ++i) {
        int j = i / 3, t = i % 3;
        wf[i]  = Wf[j*23 + 20 + t];
        wsr[i] = Ws[j*23 + 20 + t];
    }
    __syncthreads();

    int g   = threadIdx.x >> 2;       // lane-group (node within chunk)
    int sub = threadIdx.x & (VEC - 1);
    int nchunk = (cn + 63) >> 6;

    for (int p = 0; p < NS; ++p) {
        for (int c = 0; c < nchunk; ++c) {
            int nl = (c << 6) + g;
            if (nl < cn) {
                size_t idx = (size_t)p * N + (base + nl);
                int cnt = heads[idx]; if (cnt > cap) cnt = cap;

                float partial[DH];
#pragma unroll
                for (int j = 0; j < DH; ++j) partial[j] = 0.f;

                if (cnt > 0) {
                    float dr[REC];
#pragma unroll
                    for (int j = 0; j < REC; ++j) dr[j] = s_drec[nl*REC + j];

                    size_t rb = idx * cap;
                    for (int q = sub; q < cnt; q += VEC) {
                        u2v c2 = __builtin_nontemporal_load(((const u2v*)csr) + rb + q);
                        u32 w0 = c2.x;
                        int src = (int)(w0 & 0x3FFFFu);
                        float a2 = (float)(w0 >> 18) * (1.0f / 16383.0f);
                        float2 a01 = unpack_h2(c2.y);
                        float a0 = a01.x, a1 = a01.y;

                        const uint4* sp = (const uint4*)(ShU + (size_t)src * SHU);
                        uint4 A = sp[0];
                        uint4 B = sp[1];
                        uint2 C = *(const uint2*)(sp + 2);
                        u32 u[10] = {A.x, A.y, A.z, A.w, B.x, B.y, B.z, B.w, C.x, C.y};
                        float s[20];
#pragma unroll
                        for (int i = 0; i < 10; ++i) {
                            float2 f = unpack_h2(u[i]);
                            s[2*i] = f.x; s[2*i+1] = f.y;
                        }
#pragma unroll
                        for (int j = 0; j < DH; ++j) {
                            float pf = dr[j]      + s[j]      + a0*wf[j*3]  + a1*wf[j*3+1]  + a2*wf[j*3+2];
                            float ps = dr[DH + j] + s[DH + j] + a0*wsr[j*3] + a1*wsr[j*3+1] + a2*wsr[j*3+2];
                            float sg  = __builtin_amdgcn_rcpf(1.0f + __expf(-pf));           // sigmoid
                            float sp2 = fmaxf(ps, 0.f) + __logf(1.0f + __expf(-fabsf(ps)));  // softplus
                            partial[j] += sg * sp2;
                        }
                    }
                }
#pragma unroll
                for (int j = 0; j < DH; ++j) {
                    partial[j] += __shfl_xor(partial[j], 1);
                    partial[j] += __shfl_xor(partial[j], 2);
                }
                if (sub == 0 && cnt > 0) {
#pragma unroll
                    for (int j = 0; j < DH; ++j) s_acc[nl*DH + j] += partial[j];
                }
            }
        }
        __syncthreads();   // keep the wg's waves slice-aligned
    }

    for (int i = threadIdx.x; i < cn * DH; i += 256)
        accg[(size_t)base * DH + i] = s_acc[i];
}

// ---------------------------------------------------------------------------
// Overflow pass (runs after gather_persist): ~1e4 edges, global atomics.
// ---------------------------------------------------------------------------
__global__ void ovf_pass(const uint4* __restrict__ ovf, const int* __restrict__ ovfh,
                         const float* __restrict__ D, const u32* __restrict__ ShU,
                         const float* __restrict__ Wf, const float* __restrict__ Ws,
                         float* __restrict__ accg)
{
    __shared__ float wf[30], wsr[30];
    if (threadIdx.x < 30) {
        int j = threadIdx.x / 3, t = threadIdx.x % 3;
        wf[threadIdx.x]  = Wf[j*23 + 20 + t];
        wsr[threadIdx.x] = Ws[j*23 + 20 + t];
    }
    __syncthreads();

    int oc = *ovfh; if (oc > OVFCAP) oc = OVFCAP;
    for (int i = blockIdx.x * blockDim.x + threadIdx.x; i < oc;
         i += gridDim.x * blockDim.x) {
        uint4 e = ovf[i];
        int dst = (int)e.x;
        u32 w0 = e.y;
        int src = (int)(w0 & 0x3FFFFu);
        float a2 = (float)(w0 >> 18) * (1.0f / 16383.0f);
        float2 a01 = unpack_h2(e.z);
        float a0 = a01.x, a1 = a01.y;

        float dr[REC];
        const float4* dp = (const float4*)(D + (size_t)dst * REC);
#pragma unroll
        for (int k = 0; k < 5; ++k) ((float4*)dr)[k] = dp[k];

        const uint4* sp = (const uint4*)(ShU + (size_t)src * SHU);
        uint4 A = sp[0];
        uint4 B = sp[1];
        uint2 C = *(const uint2*)(sp + 2);
        u32 u[10] = {A.x, A.y, A.z, A.w, B.x, B.y, B.z, B.w, C.x, C.y};
        float s[20];
#pragma unroll
        for (int k = 0; k < 10; ++k) {
            float2 f = unpack_h2(u[k]);
            s[2*k] = f.x; s[2*k+1] = f.y;
        }
        float* ap = accg + (size_t)dst * DH;
#pragma unroll
        for (int j = 0; j < DH; ++j) {
            float pf = dr[j]      + s[j]      + a0*wf[j*3]  + a1*wf[j*3+1]  + a2*wf[j*3+2];
            float ps = dr[DH + j] + s[DH + j] + a0*wsr[j*3] + a1*wsr[j*3+1] + a2*wsr[j*3+2];
            float sg  = __builtin_amdgcn_rcpf(1.0f + __expf(-pf));
            float sp2 = fmaxf(ps, 0.f) + __logf(1.0f + __expf(-fabsf(ps)));
            atomicAdd(ap + j, sg * sp2);
        }
    }
}

// ---------------------------------------------------------------------------
// Layer-1 epilogue: h = relu(h + acc); records for layer 2
// ---------------------------------------------------------------------------
__global__ void node_mid_h(float* __restrict__ h, const float* __restrict__ acc,
                           const float* __restrict__ fW, const float* __restrict__ fb,
                           const float* __restrict__ sW, const float* __restrict__ sb,
                           float* __restrict__ D, u32* __restrict__ Sh, int N)
{
    __shared__ float lfW[230], lfb[10], lsW[230], lsb[10];
    for (int i = threadIdx.x; i < 230; i += blockDim.x) { lfW[i] = fW[i]; lsW[i] = sW[i]; }
    for (int i = threadIdx.x; i < 10;  i += blockDim.x) { lfb[i] = fb[i]; lsb[i] = sb[i]; }
    __syncthreads();
    int n = blockIdx.x * blockDim.x + threadIdx.x;
    if (n >= N) return;
    float* hp = h + (size_t)n * DH;
    const float* ap = acc + (size_t)n * DH;
    float hh[DH];
#pragma unroll
    for (int j = 0; j < DH; ++j) {
        hh[j] = fmaxf(hp[j] + ap[j], 0.f);
        hp[j] = hh[j];
    }
    compute_records_h(hh, lfW, lfb, lsW, lsb, D + (size_t)n*REC, Sh + (size_t)n*SHU);
}

// ---------------------------------------------------------------------------
// Layer-2 epilogue + pooling: segmented block-local reduction (batch sorted).
// ---------------------------------------------------------------------------
__global__ void node_pool(const float* __restrict__ h, const float* __restrict__ acc,
                          const int* __restrict__ batch,
                          float* __restrict__ gsum, float* __restrict__ gcnt, int N)
{
    __shared__ float lg[PBIN * DH];
    __shared__ float lc[PBIN];

    int base = blockIdx.x * blockDim.x;
    int n = base + threadIdx.x;

    for (int i = threadIdx.x; i < PBIN * DH; i += blockDim.x) lg[i] = 0.f;
    if (threadIdx.x < PBIN) lc[threadIdx.x] = 0.f;
    __syncthreads();

    int b0 = batch[base];   // uniform across block (sorted)

    if (n < N) {
        int b = batch[n];
        int off = b - b0;
        const float* hp = h + (size_t)n * DH;
        const float* ap = acc + (size_t)n * DH;
        float v[DH];
#pragma unroll
        for (int j = 0; j < DH; ++j) v[j] = fmaxf(hp[j] + ap[j], 0.f);

        if (off < PBIN) {
#pragma unroll
            for (int j = 0; j < DH; ++j) atomicAdd(&lg[off * DH + j], v[j]);
            atomicAdd(&lc[off], 1.f);
        } else {   // statistically impossible (256 sorted nodes span ~4 graphs)
            float* gp = gsum + (size_t)b * DH;
#pragma unroll
            for (int j = 0; j < DH; ++j) atomicAdd(gp + j, v[j]);
            atomicAdd(gcnt + b, 1.f);
        }
    }
    __syncthreads();

    for (int i = threadIdx.x; i < PBIN * DH; i += blockDim.x) {
        int g = i / DH;
        if (lc[g] > 0.f)
            atomicAdd(&gsum[(size_t)(b0 + g) * DH + (i - g * DH)], lg[i]);
    }
    if (threadIdx.x < PBIN && lc[threadIdx.x] > 0.f)
        atomicAdd(&gcnt[b0 + threadIdx.x], lc[threadIdx.x]);
}

// ---------------------------------------------------------------------------
// Fallback path kernels (fp32 atomic path; used only if ws too small / N too big)
// ---------------------------------------------------------------------------
__global__ void node_pre_f32(const float* __restrict__ x,
                             const float* __restrict__ preW, const float* __restrict__ preb,
                             const float* __restrict__ fW, const float* __restrict__ fb,
                             const float* __restrict__ sW, const float* __restrict__ sb,
                             float* __restrict__ h, float* __restrict__ D, float* __restrict__ S,
                             float* __restrict__ agg,
                             float* __restrict__ gsum, float* __restrict__ gcnt, int N, int G)
{
    __shared__ float lpW[30], lpb[10], lfW[230], lfb[10], lsW[230], lsb[10];
    for (int i = threadIdx.x; i < 30;  i += blockDim.x) lpW[i] = preW[i];
    for (int i = threadIdx.x; i < 10;  i += blockDim.x) { lpb[i] = preb[i]; lfb[i] = fb[i]; lsb[i] = sb[i]; }
    for (int i = threadIdx.x; i < 230; i += blockDim.x) { lfW[i] = fW[i]; lsW[i] = sW[i]; }
    __syncthreads();
    int n = blockIdx.x * blockDim.x + threadIdx.x;
    if (n < G * DH) gsum[n] = 0.f;
    if (n < G)      gcnt[n] = 0.f;
    if (n >= N) return;
    float x0 = x[(size_t)n*3], x1 = x[(size_t)n*3+1], x2 = x[(size_t)n*3+2];
    float hh[DH];
#pragma unroll
    for (int j = 0; j < DH; ++j)
        hh[j] = fmaxf(lpb[j] + x0*lpW[j*3] + x1*lpW[j*3+1] + x2*lpW[j*3+2], 0.f);
    float* hp = h + (size_t)n * DH;
    float* ap = agg + (size_t)n * DH;
#pragma unroll
    for (int j = 0; j < DH; ++j) { hp[j] = hh[j]; ap[j] = 0.f; }
    compute_records(hh, lfW, lfb, lsW, lsb, D + (size_t)n*REC, S + (size_t)n*REC);
}

__global__ void edge_pass(const int* __restrict__ ei, const float* __restrict__ attr,
                          const float* __restrict__ D, const float* __restrict__ S,
                          const float* __restrict__ Wf, const float* __restrict__ Ws,
                          float* __restrict__ agg, int E)
{
    __shared__ float wfe[30], wse[30];
    if (threadIdx.x < 30) {
        int j = threadIdx.x / 3, t = threadIdx.x % 3;
        wfe[threadIdx.x] = Wf[j*23 + 20 + t];
        wse[threadIdx.x] = Ws[j*23 + 20 + t];
    }
    __syncthreads();
    int e = blockIdx.x * blockDim.x + threadIdx.x;
    if (e >= E) return;
    int src = ei[e];
    int dst = ei[(size_t)E + e];
    const float* eap = attr + (size_t)e * DE;
    float ea0 = eap[0], ea1 = eap[1], ea2 = eap[2];
    float drec[REC], srec[REC];
    const float4* Dp = (const float4*)(D + (size_t)dst * REC);
    const float4* Sp = (const float4*)(S + (size_t)src * REC);
#pragma unroll
    for (int i = 0; i < 5; ++i) { ((float4*)drec)[i] = Dp[i]; ((float4*)srec)[i] = Sp[i]; }
    float* ap = agg + (size_t)dst * DH;
#pragma unroll
    for (int j = 0; j < DH; ++j) {
        float pf = drec[j]      + srec[j]      + ea0*wfe[j*3] + ea1*wfe[j*3+1] + ea2*wfe[j*3+2];
        float ps = drec[DH + j] + srec[DH + j] + ea0*wse[j*3] + ea1*wse[j*3+1] + ea2*wse[j*3+2];
        float sg = 1.0f / (1.0f + __expf(-pf));
        float sp = fmaxf(ps, 0.f) + log1pf(__expf(-fabsf(ps)));
        atomicAdd(ap + j, sg * sp);
    }
}

__global__ void node_mid(float* __restrict__ h, float* __restrict__ agg,
                         const float* __restrict__ fW, const float* __restrict__ fb,
                         const float* __restrict__ sW, const float* __restrict__ sb,
                         float* __restrict__ D, float* __restrict__ S, int N)
{
    __shared__ float lfW[230], lfb[10], lsW[230], lsb[10];
    for (int i = threadIdx.x; i < 230; i += blockDim.x) { lfW[i] = fW[i]; lsW[i] = sW[i]; }
    for (int i = threadIdx.x; i < 10;  i += blockDim.x) { lfb[i] = fb[i]; lsb[i] = sb[i]; }
    __syncthreads();
    int n = blockIdx.x * blockDim.x + threadIdx.x;
    if (n >= N) return;
    float* hp = h + (size_t)n * DH;
    float* ap = agg + (size_t)n * DH;
    float hh[DH];
#pragma unroll
    for (int j = 0; j < DH; ++j) {
        hh[j] = fmaxf(hp[j] + ap[j], 0.f);
        hp[j] = hh[j];
        ap[j] = 0.f;
    }
    compute_records(hh, lfW, lfb, lsW, lsb, D + (size_t)n*REC, S + (size_t)n*REC);
}

__global__ void node_post(const float* __restrict__ h, const float* __restrict__ agg,
                          const int* __restrict__ batch,
                          float* __restrict__ gsum, float* __restrict__ gcnt, int N)
{
    int n = blockIdx.x * blockDim.x + threadIdx.x;
    if (n >= N) return;
    int b = batch[n];
    const float* hp = h + (size_t)n * DH;
    const float* ap = agg + (size_t)n * DH;
    float* gp = gsum + (size_t)b * DH;
#pragma unroll
    for (int j = 0; j < DH; ++j)
        atomicAdd(gp + j, fmaxf(hp[j] + ap[j], 0.f));
    atomicAdd(gcnt + b, 1.f);
}

// ---------------------------------------------------------------------------
// MLP head: one block (128 threads) per graph.
// ---------------------------------------------------------------------------
__global__ void mlp_head(const float* __restrict__ gsum, const float* __restrict__ gcnt,
                         const float* __restrict__ fc1W, const float* __restrict__ fc1b,
                         const float* __restrict__ fc2W, const float* __restrict__ fc2b,
                         const float* __restrict__ outW, const float* __restrict__ outb,
                         float* __restrict__ out, int G)
{
    __shared__ float g[DH], a1[128], a2[128];
    int gid = blockIdx.x;
    int t = threadIdx.x;
    if (t < DH) {
        float c = fmaxf(gcnt[gid], 1.0f);
        g[t] = gsum[(size_t)gid*DH + t] / c;
    }
    __syncthreads();
    {
        float acc = fc1b[t];
        const float* w = fc1W + (size_t)t * DH;
#pragma unroll
        for (int k = 0; k < DH; ++k) acc += w[k] * g[k];
        a1[t] = fmaxf(acc, 0.f);
    }
    __syncthreads();
    {
        float acc = fc2b[t];
        const float* w = fc2W + (size_t)t * 128;
#pragma unroll 8
        for (int k = 0; k < 128; ++k) acc += w[k] * a1[k];
        a2[t] = fmaxf(acc, 0.f);
    }
    __syncthreads();
    if (t < 3) {
        float acc = outb[t];
        const float* w = outW + (size_t)t * 128;
#pragma unroll 8
        for (int k = 0; k < 128; ++k) acc += w[k] * a2[k];
        out[(size_t)gid*3 + t] = acc;
    }
}

// ---------------------------------------------------------------------------
extern "C" void kernel_launch(void* const* d_in, const int* in_sizes, int n_in,
                              void* d_out, int out_size, void* d_ws, size_t ws_size,
                              hipStream_t stream)
{
    const float* x     = (const float*)d_in[0];
    const int*   ei    = (const int*)  d_in[1];
    const float* attr  = (const float*)d_in[2];
    const int*   batch = (const int*)  d_in[3];
    const float* preW  = (const float*)d_in[4];
    const float* preb  = (const float*)d_in[5];
    const float* f1W   = (const float*)d_in[6];
    const float* f1b   = (const float*)d_in[7];
    const float* s1W   = (const float*)d_in[8];
    const float* s1b   = (const float*)d_in[9];
    const float* f2W   = (const float*)d_in[10];
    const float* f2b   = (const float*)d_in[11];
    const float* s2W   = (const float*)d_in[12];
    const float* s2b   = (const float*)d_in[13];
    const float* fc1W  = (const float*)d_in[14];
    const float* fc1b  = (const float*)d_in[15];
    const float* fc2W  = (const float*)d_in[16];
    const float* fc2b  = (const float*)d_in[17];
    const float* outW  = (const float*)d_in[18];
    const float* outb  = (const float*)d_in[19];

    const int N = in_sizes[0] / DIN;          // 200000
    const int E = in_sizes[1] / 2;            // 6400000
    const int G = out_size / 3;               // 1024
    const int M = NS * N;                     // bucket-head table size
    const int npw = (N + WGN - 1) / WGN;      // 131 dst nodes per persistent wg

    const int TB = 256;
    const int nb = (N + TB - 1) / TB;
    const int eb = (E + TB - 1) / TB;
    const int zb = ((M > G * DH ? M : G * DH) + TB - 1) / TB;

    // ---- workspace layout (csr capacity computed from remaining budget) ----
    size_t f_off = 0;
    float* ws = (float*)d_ws;
    float* h    = ws + f_off; f_off += (size_t)N * DH;
    float* D    = ws + f_off; f_off += (size_t)N * REC;
    f_off = (f_off + 15) & ~(size_t)15;                        // 64B-align Sh
    u32*   Sh   = (u32*)(ws + f_off); f_off += (size_t)N * SHU;
    float* acc  = ws + f_off; f_off += (size_t)N * DH;
    float* gsum = ws + f_off; f_off += (size_t)G * DH;
    float* gcnt = ws + f_off; f_off += G;
    f_off = (f_off + 15) & ~(size_t)15;
    int* heads  = (int*)(ws + f_off); f_off += M;
    int* ovfh   = (int*)(ws + f_off); f_off += 1;
    f_off = (f_off + 15) & ~(size_t)15;
    uint4* ovf  = (uint4*)(ws + f_off); f_off += (size_t)OVFCAP * 4;
    f_off = (f_off + 15) & ~(size_t)15;
    uint2* csr  = (uint2*)(ws + f_off);

    size_t core_bytes = f_off * sizeof(float);
    long long budget = (long long)ws_size - (long long)core_bytes;
    int cap = 0;
    if (budget > 0) cap = (int)(budget / ((long long)M * 8));
    if (cap > 16) cap = 16;

    if (cap >= 6 && npw <= MAXNPW && N < (1 << 18)) {
        // ===== capacity-bucket + persistent slice-walk path (R0-proven) =====
        zero_small<<<zb, TB, 0, stream>>>(heads, M, ovfh, gsum, gcnt, G);
        node_pre_h<<<nb, TB, 0, stream>>>(x, preW, preb, f1W, f1b, s1W, s1b,
                                          h, D, Sh, N);
        scatter_cap<<<eb, TB, 0, stream>>>(ei, attr, heads, csr, ovf, ovfh, E, N, cap);

        gather_persist<<<WGN, 256, 0, stream>>>(heads, csr, cap, D, Sh,
                                                f1W, s1W, acc, N, npw);
        ovf_pass<<<256, 256, 0, stream>>>(ovf, ovfh, D, Sh, f1W, s1W, acc);
        node_mid_h<<<nb, TB, 0, stream>>>(h, acc, f2W, f2b, s2W, s2b, D, Sh, N);

        gather_persist<<<WGN, 256, 0, stream>>>(heads, csr, cap, D, Sh,
                                                f2W, s2W, acc, N, npw);
        ovf_pass<<<256, 256, 0, stream>>>(ovf, ovfh, D, Sh, f2W, s2W, acc);
        node_pool<<<nb, TB, 0, stream>>>(h, acc, batch, gsum, gcnt, N);
        mlp_head<<<G, 128, 0, stream>>>(gsum, gcnt, fc1W, fc1b, fc2W, fc2b,
                                        outW, outb, (float*)d_out, G);
    } else {
        // ===== fallback: fp32 atomic path =====
        size_t o = 0;
        float* fh    = ws + o; o += (size_t)N * DH;
        float* agg   = ws + o; o += (size_t)N * DH;
        float* fD    = ws + o; o += (size_t)N * REC;
        float* fS    = ws + o; o += (size_t)N * REC;
        float* fgsum = ws + o; o += (size_t)G * DH;
        float* fgcnt = ws + o; o += G;

        node_pre_f32<<<nb, TB, 0, stream>>>(x, preW, preb, f1W, f1b, s1W, s1b,
                                            fh, fD, fS, agg, fgsum, fgcnt, N, G);
        edge_pass<<<eb, TB, 0, stream>>>(ei, attr, fD, fS, f1W, s1W, agg, E);
        node_mid<<<nb, TB, 0, stream>>>(fh, agg, f2W, f2b, s2W, s2b, fD, fS, N);
        edge_pass<<<eb, TB, 0, stream>>>(ei, attr, fD, fS, f2W, s2W, agg, E);
        node_post<<<nb, TB, 0, stream>>>(fh, agg, batch, fgsum, fgcnt, N);
        mlp_head<<<G, 128, 0, stream>>>(fgsum, fgcnt, fc1W, fc1b, fc2W, fc2b,
                                        outW, outb, (float*)d_out, G);
    }
}